// Round 4
// 1771.809 us; speedup vs baseline: 1.1618x; 1.1618x over previous
//
#include <hip/hip_runtime.h>
#include <math.h>

#define Sn 2048
#define Dm 2048
#define Hn 16
#define KVn 8
#define HD 128
#define FFn 6144
#define PK 614

#define BM 64
#define BN 64
#define BK 16

typedef __attribute__((ext_vector_type(8))) short short8;
typedef __attribute__((ext_vector_type(4))) short s16x4;
typedef __attribute__((ext_vector_type(4))) float f32x4;

__device__ __forceinline__ short f2bf(float f) {   // RNE fp32->bf16
    unsigned u = __float_as_uint(f);
    u += 0x7fff + ((u >> 16) & 1);
    return (short)(u >> 16);
}

__device__ __forceinline__ float bf2f(short h) {
    return __uint_as_float((unsigned)(unsigned short)h << 16);
}

__device__ __forceinline__ void gload16(const void* g, void* l) {
    __builtin_amdgcn_global_load_lds((const __attribute__((address_space(1))) void*)g,
                                     (__attribute__((address_space(3))) void*)l, 16, 0, 0);
}

// ---------------------------------------------------------------------------
// fp32 vector GEMM. Used ONLY for the K projection: the fp64 importance path
// needs kbuf at full fp32 accuracy AND bit-stability (ordering of near-tie
// importance values). DO NOT change blocking/accumulation order.
// ---------------------------------------------------------------------------
template<typename ACC, int MODE>
__global__ __launch_bounds__(256)
void gemm_k(const float* __restrict__ A, int lda, long long strideA,
            const float* __restrict__ B, int ldb, long long strideB, int bshift,
            float* __restrict__ C, int ldc, long long strideC,
            const float* __restrict__ resid,
            int M, int N, int K, float alpha, int causal)
{
    const int bx = blockIdx.x, by = blockIdx.y, bz = blockIdx.z;
    const int bm0 = by * BM, bn0 = bx * BN;
    if (MODE == 1 && causal == 1 && bn0 > bm0 + BM - 1) return;

    A += (long long)bz * strideA;
    B += (long long)(bz >> bshift) * strideB;
    C += (long long)bz * strideC;

    __shared__ float As[BK][BM + 4];
    __shared__ float Bs[BK][BN + 4];

    const int tid = threadIdx.x;
    const int tx = tid & 15, ty = tid >> 4;

    ACC acc[4][4];
    #pragma unroll
    for (int i = 0; i < 4; i++)
        #pragma unroll
        for (int j = 0; j < 4; j++) acc[i][j] = (ACC)0;

    for (int k0 = 0; k0 < K; k0 += BK) {
        {
            int c = tid & 15, r0 = tid >> 4;
            #pragma unroll
            for (int i = 0; i < 4; i++) {
                int r = r0 + 16 * i;
                As[c][r] = A[(long long)(bm0 + r) * lda + (k0 + c)];
            }
        }
        if (MODE == 1) {
            int c = tid & 15, r0 = tid >> 4;
            #pragma unroll
            for (int i = 0; i < 4; i++) {
                int r = r0 + 16 * i;
                Bs[c][r] = B[(long long)(bn0 + r) * ldb + (k0 + c)];
            }
        } else {
            int c = tid & 63, r0 = tid >> 6;
            #pragma unroll
            for (int i = 0; i < 4; i++) {
                int r = r0 + 4 * i;
                Bs[r][c] = B[(long long)(k0 + r) * ldb + (bn0 + c)];
            }
        }
        __syncthreads();
        #pragma unroll
        for (int kk = 0; kk < BK; kk++) {
            float4 av = *(const float4*)&As[kk][ty * 4];
            float4 bv = *(const float4*)&Bs[kk][tx * 4];
            float a_[4] = {av.x, av.y, av.z, av.w};
            float b_[4] = {bv.x, bv.y, bv.z, bv.w};
            #pragma unroll
            for (int i = 0; i < 4; i++)
                #pragma unroll
                for (int j = 0; j < 4; j++)
                    acc[i][j] += (ACC)a_[i] * (ACC)b_[j];
        }
        __syncthreads();
    }

    #pragma unroll
    for (int i = 0; i < 4; i++) {
        int m = bm0 + ty * 4 + i;
        #pragma unroll
        for (int j = 0; j < 4; j++) {
            int n = bn0 + tx * 4 + j;
            float val = (float)(acc[i][j] * (ACC)alpha);
            if (resid) val += resid[(long long)m * ldc + n];
            C[(long long)m * ldc + n] = val;
        }
    }
}

// ---------------------------------------------------------------------------
// bf16 MFMA GEMM, m97 structure. 128x128 tile, BK=64, global_load_lds(16B).
// A[m][k] bf16 row-major, B as Bt[n][k] bf16 row-major.
// MODE 0: fp32 C (+resid). MODE 1: dual-B, C = bf16(silu(A*B) * (A*B2)).
// MODE 2: bf16 C transposed (C[n*ldc + m]) — used for Vt.
// ---------------------------------------------------------------------------
template<int MODE>
__global__ __launch_bounds__(256)
void mgemm_k(const short* __restrict__ A, int lda,
             const short* __restrict__ B, int ldb,
             const short* __restrict__ B2,
             float* __restrict__ Cf, short* __restrict__ Cb, int ldc,
             const float* __restrict__ resid, int K)
{
    __shared__ short As[128 * 64];
    __shared__ short Bs[128 * 64];
    __shared__ short B2s[(MODE == 1) ? 128 * 64 : 16];

    const int tid = threadIdx.x, lane = tid & 63, wv = tid >> 6;
    const int wm = wv & 1, wn = wv >> 1;
    const int l15 = lane & 15, q4 = lane >> 4;
    const int bm0 = blockIdx.y * 128, bn0 = blockIdx.x * 128;

    f32x4 acc[4][4];
    f32x4 acc2[(MODE == 1) ? 4 : 1][(MODE == 1) ? 4 : 1];
    #pragma unroll
    for (int i = 0; i < 4; i++)
        #pragma unroll
        for (int j = 0; j < 4; j++) {
            acc[i][j] = (f32x4)0.0f;
            if constexpr (MODE == 1) acc2[i][j] = (f32x4)0.0f;
        }

    for (int k0 = 0; k0 < K; k0 += 64) {
        #pragma unroll
        for (int r = 0; r < 4; r++) {
            int c = (wv * 4 + r) * 64 + lane;          // 16B chunk id
            int row = c >> 3, co = (c & 7) * 8;
            gload16(A + (size_t)(bm0 + row) * lda + k0 + co, (char*)As + (size_t)c * 16);
            gload16(B + (size_t)(bn0 + row) * ldb + k0 + co, (char*)Bs + (size_t)c * 16);
            if constexpr (MODE == 1)
                gload16(B2 + (size_t)(bn0 + row) * ldb + k0 + co, (char*)B2s + (size_t)c * 16);
        }
        __syncthreads();
        #pragma unroll
        for (int kk = 0; kk < 2; kk++) {
            short8 af[4], bfr[4], b2f[4];
            #pragma unroll
            for (int i = 0; i < 4; i++)
                af[i] = *(const short8*)&As[(size_t)(wm * 64 + i * 16 + l15) * 64 + kk * 32 + q4 * 8];
            #pragma unroll
            for (int j = 0; j < 4; j++) {
                bfr[j] = *(const short8*)&Bs[(size_t)(wn * 64 + j * 16 + l15) * 64 + kk * 32 + q4 * 8];
                if constexpr (MODE == 1)
                    b2f[j] = *(const short8*)&B2s[(size_t)(wn * 64 + j * 16 + l15) * 64 + kk * 32 + q4 * 8];
            }
            #pragma unroll
            for (int i = 0; i < 4; i++)
                #pragma unroll
                for (int j = 0; j < 4; j++) {
                    acc[i][j] = __builtin_amdgcn_mfma_f32_16x16x32_bf16(af[i], bfr[j], acc[i][j], 0, 0, 0);
                    if constexpr (MODE == 1)
                        acc2[i][j] = __builtin_amdgcn_mfma_f32_16x16x32_bf16(af[i], b2f[j], acc2[i][j], 0, 0, 0);
                }
        }
        __syncthreads();
    }

    #pragma unroll
    for (int i = 0; i < 4; i++)
        #pragma unroll
        for (int j = 0; j < 4; j++)
            #pragma unroll
            for (int r = 0; r < 4; r++) {
                int m = bm0 + wm * 64 + i * 16 + q4 * 4 + r;   // C/D: col=lane&15, row=q4*4+reg
                int n = bn0 + wn * 64 + j * 16 + l15;
                float vv = acc[i][j][r];
                if constexpr (MODE == 0) {
                    if (resid) vv += resid[(size_t)m * ldc + n];
                    Cf[(size_t)m * ldc + n] = vv;
                } else if constexpr (MODE == 1) {
                    float u = acc2[i][j][r];
                    Cb[(size_t)m * ldc + n] = f2bf(vv / (1.0f + expf(-vv)) * u);
                } else {
                    Cb[(size_t)n * ldc + m] = f2bf(vv);
                }
            }
}

// ---------------------------------------------------------------------------
// Split-bf16 (Markidis) fp32-accurate GEMM on MFMA.
// C = alpha * (Ahi*Bhi + Ahi*Blo + Alo*Bhi), fp32 accumulate. K' = 3K.
// ---------------------------------------------------------------------------
__global__ __launch_bounds__(256)
void msplit_k(const short* __restrict__ Ah, const short* __restrict__ Al,
              int lda, long long strideA,
              const short* __restrict__ Bh, const short* __restrict__ Bl,
              int ldb, long long strideB, int bshift,
              float* __restrict__ C, int ldc, long long strideC,
              float alpha, int K, int causal)
{
    const int bm0 = blockIdx.y * 128, bn0 = blockIdx.x * 128;
    if (causal && bn0 > bm0 + 127) return;
    const int bz = blockIdx.z;
    const long long aoff = (long long)bz * strideA;
    const long long boff = (long long)(bz >> bshift) * strideB;
    Ah += aoff; Al += aoff;
    Bh += boff; Bl += boff;
    C += (long long)bz * strideC;

    __shared__ short As[128 * 64];
    __shared__ short Bs[128 * 64];

    const int tid = threadIdx.x, lane = tid & 63, wv = tid >> 6;
    const int wm = wv & 1, wn = wv >> 1;
    const int l15 = lane & 15, q4 = lane >> 4;

    f32x4 acc[4][4];
    #pragma unroll
    for (int i = 0; i < 4; i++)
        #pragma unroll
        for (int j = 0; j < 4; j++) acc[i][j] = (f32x4)0.0f;

    const int K3 = 3 * K;
    for (int k0 = 0; k0 < K3; k0 += 64) {
        const short* Ap = Ah;
        const short* Bp = Bh;
        int kb = k0;                       // wave-uniform term select
        if (k0 >= 2 * K)      { Ap = Al; kb = k0 - 2 * K; }
        else if (k0 >= K)     { Bp = Bl; kb = k0 - K; }
        #pragma unroll
        for (int r = 0; r < 4; r++) {
            int c = (wv * 4 + r) * 64 + lane;
            int row = c >> 3, co = (c & 7) * 8;
            gload16(Ap + (size_t)(bm0 + row) * lda + kb + co, (char*)As + (size_t)c * 16);
            gload16(Bp + (size_t)(bn0 + row) * ldb + kb + co, (char*)Bs + (size_t)c * 16);
        }
        __syncthreads();
        #pragma unroll
        for (int kk = 0; kk < 2; kk++) {
            short8 af[4], bfr[4];
            #pragma unroll
            for (int i = 0; i < 4; i++)
                af[i] = *(const short8*)&As[(size_t)(wm * 64 + i * 16 + l15) * 64 + kk * 32 + q4 * 8];
            #pragma unroll
            for (int j = 0; j < 4; j++)
                bfr[j] = *(const short8*)&Bs[(size_t)(wn * 64 + j * 16 + l15) * 64 + kk * 32 + q4 * 8];
            #pragma unroll
            for (int i = 0; i < 4; i++)
                #pragma unroll
                for (int j = 0; j < 4; j++)
                    acc[i][j] = __builtin_amdgcn_mfma_f32_16x16x32_bf16(af[i], bfr[j], acc[i][j], 0, 0, 0);
        }
        __syncthreads();
    }

    #pragma unroll
    for (int i = 0; i < 4; i++)
        #pragma unroll
        for (int j = 0; j < 4; j++)
            #pragma unroll
            for (int r = 0; r < 4; r++) {
                int m = bm0 + wm * 64 + i * 16 + q4 * 4 + r;
                int n = bn0 + wn * 64 + j * 16 + l15;
                C[(size_t)m * ldc + n] = acc[i][j][r] * alpha;
            }
}

// ---------------------------------------------------------------------------
// ctx = P(fp32, causal) . Vt(bf16). 64-row tiles for causal load balance:
// grid (1, Sn/64, Hn), 512 blocks, 32 KB LDS. A staged fp32 -> cvt in-reg.
// Reads P only at j < Keff <= row's diagonal-128-block end (softmax-written).
// ---------------------------------------------------------------------------
__global__ __launch_bounds__(256)
void ctx_k(const float* __restrict__ P, const short* __restrict__ Vt,
           short* __restrict__ Cb)
{
    __shared__ float Af[64 * 64];      // 16 KB
    __shared__ short Bs[128 * 64];     // 16 KB

    const int h = blockIdx.z;
    const float* A = P + (size_t)h * Sn * Sn;
    const short* B = Vt + (size_t)(h >> 1) * HD * Sn;

    const int tid = threadIdx.x, lane = tid & 63, wv = tid >> 6;
    const int wm = wv & 1, wn = wv >> 1;
    const int l15 = lane & 15, q4 = lane >> 4;
    const int bm0 = blockIdx.y * 64;
    const int Keff = bm0 + 64;         // causal extent (rounded to tile)

    f32x4 acc[2][4];
    #pragma unroll
    for (int i = 0; i < 2; i++)
        #pragma unroll
        for (int j = 0; j < 4; j++) acc[i][j] = (f32x4)0.0f;

    for (int k0 = 0; k0 < Keff; k0 += 64) {
        #pragma unroll
        for (int r = 0; r < 4; r++) {          // A fp32: 64x64 = 1024 chunks
            int c = (wv * 4 + r) * 64 + lane;
            int row = c >> 4, co = (c & 15) * 4;
            gload16(A + (size_t)(bm0 + row) * Sn + k0 + co, (char*)Af + (size_t)c * 16);
        }
        #pragma unroll
        for (int r = 0; r < 4; r++) {          // B bf16: 128x64 = 1024 chunks
            int c = (wv * 4 + r) * 64 + lane;
            int row = c >> 3, co = (c & 7) * 8;
            gload16(B + (size_t)row * Sn + k0 + co, (char*)Bs + (size_t)c * 16);
        }
        __syncthreads();
        #pragma unroll
        for (int kk = 0; kk < 2; kk++) {
            short8 af[2], bfr[4];
            #pragma unroll
            for (int i = 0; i < 2; i++) {
                const float* ap = &Af[(size_t)(wm * 32 + i * 16 + l15) * 64 + kk * 32 + q4 * 8];
                f32x4 a0 = *(const f32x4*)ap;
                f32x4 a1 = *(const f32x4*)(ap + 4);
                short8 t;
                t[0] = f2bf(a0[0]); t[1] = f2bf(a0[1]); t[2] = f2bf(a0[2]); t[3] = f2bf(a0[3]);
                t[4] = f2bf(a1[0]); t[5] = f2bf(a1[1]); t[6] = f2bf(a1[2]); t[7] = f2bf(a1[3]);
                af[i] = t;
            }
            #pragma unroll
            for (int j = 0; j < 4; j++)
                bfr[j] = *(const short8*)&Bs[(size_t)(wn * 64 + j * 16 + l15) * 64 + kk * 32 + q4 * 8];
            #pragma unroll
            for (int i = 0; i < 2; i++)
                #pragma unroll
                for (int j = 0; j < 4; j++)
                    acc[i][j] = __builtin_amdgcn_mfma_f32_16x16x32_bf16(af[i], bfr[j], acc[i][j], 0, 0, 0);
        }
        __syncthreads();
    }

    #pragma unroll
    for (int i = 0; i < 2; i++)
        #pragma unroll
        for (int j = 0; j < 4; j++)
            #pragma unroll
            for (int r = 0; r < 4; r++) {
                int m = bm0 + wm * 32 + i * 16 + q4 * 4 + r;
                int n = wn * 64 + j * 16 + l15;
                Cb[(size_t)m * Dm + h * HD + n] = f2bf(acc[i][j][r]);
            }
}

// ---------------------------------------------------------------------------
// Transpose-cast: Wt[c][r] (bf16 hi) = W[row0+r][col0+c] (fp32); optional lo.
// ---------------------------------------------------------------------------
__global__ __launch_bounds__(256)
void castT_k(const float* __restrict__ W, int ldw, int row0, int col0,
             short* __restrict__ Wt, short* __restrict__ Wlo, int ldt)
{
    __shared__ float t[64][65];
    const int tr = threadIdx.x >> 6, tc = threadIdx.x & 63;
    const int gr = blockIdx.y * 64, gc = blockIdx.x * 64;
    #pragma unroll
    for (int rr = tr; rr < 64; rr += 4)
        t[rr][tc] = W[(size_t)(row0 + gr + rr) * ldw + col0 + gc + tc];
    __syncthreads();
    #pragma unroll
    for (int cc = tr; cc < 64; cc += 4) {
        float v = t[tc][cc];
        short h = f2bf(v);
        size_t off = (size_t)(gc + cc) * ldt + gr + tc;
        Wt[off] = h;
        if (Wlo) Wlo[off] = f2bf(v - bf2f(h));
    }
}

// ---------------------------------------------------------------------------
// Elementwise hi/lo split of an fp32 buffer (n4 = count/4 float4 quads).
// ---------------------------------------------------------------------------
__global__ __launch_bounds__(256)
void split_k(const float* __restrict__ in, short* __restrict__ hi,
             short* __restrict__ lo, int n4)
{
    int i = blockIdx.x * 256 + threadIdx.x;
    if (i >= n4) return;
    f32x4 v = *(const f32x4*)(in + (size_t)i * 4);
    s16x4 h, l;
    #pragma unroll
    for (int j = 0; j < 4; j++) {
        short hh = f2bf(v[j]);
        h[j] = hh;
        l[j] = f2bf(v[j] - bf2f(hh));
    }
    *(s16x4*)(hi + (size_t)i * 4) = h;
    *(s16x4*)(lo + (size_t)i * 4) = l;
}

// ---------------------------------------------------------------------------
// RMSNorm: optional fp32 out and/or bf16 hi out and/or bf16 lo out.
// ---------------------------------------------------------------------------
__global__ __launch_bounds__(256)
void rmsnorm_k(const float* __restrict__ in, const float* __restrict__ w,
               float* __restrict__ o, short* __restrict__ ob,
               short* __restrict__ obl)
{
    const int row = blockIdx.x;
    const float* x = in + (long long)row * Dm;
    const int tid = threadIdx.x;
    double ss = 0.0;
    #pragma unroll
    for (int rb = 0; rb < 8; rb++) {
        float t = x[tid + rb * 256];
        ss += (double)t * (double)t;
    }
    #pragma unroll
    for (int off = 32; off > 0; off >>= 1) ss += __shfl_xor(ss, off, 64);
    __shared__ double sh[4];
    int lane = tid & 63, wvv = tid >> 6;
    if (lane == 0) sh[wvv] = ss;
    __syncthreads();
    double tot = sh[0] + sh[1] + sh[2] + sh[3];
    double scale = 1.0 / sqrt(tot / (double)Dm + (double)1e-6f);
    #pragma unroll
    for (int rb = 0; rb < 8; rb++) {
        int j = tid + rb * 256;
        float val = (float)((double)x[j] * scale * (double)w[j]);
        if (o)  o[(long long)row * Dm + j] = val;
        if (ob) {
            short h = f2bf(val);
            ob[(long long)row * Dm + j] = h;
            if (obl) obl[(long long)row * Dm + j] = f2bf(val - bf2f(h));
        }
    }
}

// ---------------------------------------------------------------------------
__global__ __launch_bounds__(256)
void rope_table_k(const int* __restrict__ positions,
                  double* __restrict__ ct, double* __restrict__ st)
{
    int idx = blockIdx.x * 256 + threadIdx.x;
    if (idx >= Sn * 64) return;
    int s = idx >> 6, j = idx & 63;
    float e = (float)j * (1.0f / 64.0f);
    float p32 = (float)pow(1.0e6, (double)e);
    float invf = (float)(1.0 / (double)p32);
    float ang = (float)positions[s] * invf;
    ct[idx] = cos((double)ang);
    st[idx] = sin((double)ang);
}

__global__ __launch_bounds__(128)
void qknorm_rope_k(float* __restrict__ buf, int ld, int nh,
                   const float* __restrict__ w,
                   const double* __restrict__ ct, const double* __restrict__ st)
{
    const int b = blockIdx.x;
    const int h = b % nh, s = b / nh;
    float* p = buf + (long long)s * ld + h * HD;
    const int d = threadIdx.x;
    const int pd = (d < 64) ? d + 64 : d - 64;
    float a = p[d];
    float pv = p[pd];
    double ss = (double)a * (double)a;
    #pragma unroll
    for (int o = 32; o > 0; o >>= 1) ss += __shfl_xor(ss, o, 64);
    __shared__ double sh[2];
    if ((d & 63) == 0) sh[d >> 6] = ss;
    __syncthreads();
    double tot = sh[0] + sh[1];
    double scale = 1.0 / sqrt(tot / (double)HD + (double)1e-6f);
    double xn = (double)a * scale * (double)w[d];
    double pn = (double)pv * scale * (double)w[pd];
    double rot = (d < 64) ? -pn : pn;
    int j = d & 63;
    double c = ct[s * 64 + j], snv = st[s * 64 + j];
    p[d] = (float)(xn * c + rot * snv);
}

// hp last-row q projection: block b -> n in [64b, 64b+64)
__global__ __launch_bounds__(256)
void qlast_proj_k(const float* __restrict__ x, const float* __restrict__ Wq,
                  double* __restrict__ qlast)
{
    __shared__ double part[4][64];
    const int kq = threadIdx.x >> 6, nn = threadIdx.x & 63;
    const int n = blockIdx.x * 64 + nn;
    const float* xr = x + (size_t)(Sn - 1) * Dm;
    double acc = 0.0;
    for (int k = kq; k < Dm; k += 4)
        acc += (double)xr[k] * (double)Wq[(size_t)k * Dm + n];
    part[kq][nn] = acc;
    __syncthreads();
    if (kq == 0)
        qlast[n] = part[0][nn] + part[1][nn] + part[2][nn] + part[3][nn];
}

__global__ __launch_bounds__(128)
void qlast_nr_k(const double* __restrict__ qlast, const float* __restrict__ w,
                const double* __restrict__ ct, const double* __restrict__ st,
                double* __restrict__ qhat)
{
    const int h = blockIdx.x, d = threadIdx.x;
    const int pd = (d < 64) ? d + 64 : d - 64;
    double a = qlast[h * HD + d];
    double pv = qlast[h * HD + pd];
    double ss = a * a;
    #pragma unroll
    for (int o = 32; o > 0; o >>= 1) ss += __shfl_xor(ss, o, 64);
    __shared__ double sh[2];
    if ((d & 63) == 0) sh[d >> 6] = ss;
    __syncthreads();
    double tot = sh[0] + sh[1];
    double scale = 1.0 / sqrt(tot / (double)HD + (double)1e-6f);
    double xn = a * scale * (double)w[d];
    double pn = pv * scale * (double)w[pd];
    double rot = (d < 64) ? -pn : pn;
    int j = d & 63;
    double c = ct[(Sn - 1) * 64 + j], snv = st[(Sn - 1) * 64 + j];
    qhat[h * HD + d] = xn * c + rot * snv;
}

__global__ __launch_bounds__(256)
void imp_scores_k(const double* __restrict__ qhat, const float* __restrict__ khat,
                  double* __restrict__ phead)
{
    const int h = blockIdx.x, kv = h >> 1;
    __shared__ double sc[Sn];
    __shared__ double qv[HD];
    __shared__ double sh[4];
    const int tid = threadIdx.x;
    if (tid < HD) qv[tid] = qhat[h * HD + tid];
    __syncthreads();
    const double s128 = (double)sqrtf(128.0f);
    for (int j = tid; j < Sn; j += 256) {
        const float* kr = khat + (long long)j * (KVn * HD) + kv * HD;
        double acc = 0.0;
        #pragma unroll 8
        for (int dd = 0; dd < HD; dd++) acc += qv[dd] * (double)kr[dd];
        sc[j] = acc / s128;
    }
    __syncthreads();
    double m = -1.0e300;
    for (int j = tid; j < Sn; j += 256) m = fmax(m, sc[j]);
    #pragma unroll
    for (int o = 32; o > 0; o >>= 1) m = fmax(m, __shfl_xor(m, o, 64));
    if ((tid & 63) == 0) sh[tid >> 6] = m;
    __syncthreads();
    m = fmax(fmax(sh[0], sh[1]), fmax(sh[2], sh[3]));
    __syncthreads();
    double ssum = 0.0;
    for (int j = tid; j < Sn; j += 256) {
        double e = exp(sc[j] - m);
        sc[j] = e;
        ssum += e;
    }
    #pragma unroll
    for (int o = 32; o > 0; o >>= 1) ssum += __shfl_xor(ssum, o, 64);
    if ((tid & 63) == 0) sh[tid >> 6] = ssum;
    __syncthreads();
    double tot = sh[0] + sh[1] + sh[2] + sh[3];
    for (int j = tid; j < Sn; j += 256)
        phead[(long long)h * Sn + j] = sc[j] / tot;
}

__global__ __launch_bounds__(1024)
void imp_sort_k(const double* __restrict__ phead, float* __restrict__ out_idx)
{
    __shared__ unsigned long long keys[Sn];
    const int tid = threadIdx.x;
    for (int j = tid; j < Sn; j += 1024) {
        double s = 0.0;
        #pragma unroll
        for (int h = 0; h < Hn; h++) s += phead[(long long)h * Sn + j];
        float imp = (float)(s * (1.0 / 16.0));
        if (j == Sn - 1) imp = __builtin_inff();
        unsigned u = __float_as_uint(imp);
        keys[j] = ((unsigned long long)u << 32) | (unsigned)j;
    }
    __syncthreads();
    for (int k = 2; k <= Sn; k <<= 1) {
        for (int jj = k >> 1; jj > 0; jj >>= 1) {
            for (int i = tid; i < Sn; i += 1024) {
                int p = i ^ jj;
                if (p > i) {
                    unsigned long long a = keys[i], b = keys[p];
                    bool up = ((i & k) == 0);
                    if ((a > b) == up) { keys[i] = b; keys[p] = a; }
                }
            }
            __syncthreads();
        }
    }
    if (tid < PK)
        out_idx[tid] = (float)(unsigned)(keys[tid] & 0xffffffffULL);
}

// ---------------------------------------------------------------------------
// Causal softmax, wave-per-row, float4, no LDS/barriers. Writes only
// j < E = 128*ceil((i+1)/128): columns beyond E were never written by the
// scores GEMM (harness pre-zeroes the output buffer) and are never read by
// ctx_k (which reads j < Keff <= E). grid = Hn*Sn/4, block = 256 (4 waves).
// nit = ceil(E/256); lanes with j4 >= E are masked (E=128 -> half-wave).
// ---------------------------------------------------------------------------
__global__ __launch_bounds__(256)
void softmax_k(float* __restrict__ attn)
{
    const int wv = threadIdx.x >> 6, lane = threadIdx.x & 63;
    const long long row = (long long)blockIdx.x * 4 + wv;
    const int i = (int)(row & (Sn - 1));
    float* p = attn + row * Sn;
    const int E = ((i >> 7) + 1) << 7;         // diagonal-block end (<= 2048)
    const int nit = (E + 255) >> 8;            // ceil(E/256) float4-iters (1..8)

    f32x4 v[8];
    float mx = -1e30f;
    #pragma unroll
    for (int it = 0; it < 8; it++) {
        if (it < nit) {
            int j4 = (it * 64 + lane) * 4;
            f32x4 t;
            if (j4 < E) {
                t = *(const f32x4*)(p + j4);
                #pragma unroll
                for (int c = 0; c < 4; c++) {
                    if (j4 + c > i) t[c] = -1e30f;  // mask garbage in diag block
                    mx = fmaxf(mx, t[c]);
                }
            } else {
                t = (f32x4)(-1e30f);               // lane beyond row extent
            }
            v[it] = t;
        }
    }
    #pragma unroll
    for (int o = 32; o > 0; o >>= 1) mx = fmaxf(mx, __shfl_xor(mx, o, 64));

    float sum = 0.0f;
    #pragma unroll
    for (int it = 0; it < 8; it++) {
        if (it < nit) {
            f32x4 t = v[it];
            #pragma unroll
            for (int c = 0; c < 4; c++) {
                float e = (t[c] > -1e29f) ? expf(t[c] - mx) : 0.0f;
                t[c] = e;
                sum += e;
            }
            v[it] = t;
        }
    }
    #pragma unroll
    for (int o = 32; o > 0; o >>= 1) sum += __shfl_xor(sum, o, 64);
    float inv = 1.0f / sum;

    #pragma unroll
    for (int it = 0; it < 8; it++) {
        if (it < nit) {
            int j4 = (it * 64 + lane) * 4;
            if (j4 < E) {
                f32x4 t = v[it];
                t[0] *= inv; t[1] *= inv; t[2] *= inv; t[3] *= inv;
                *(f32x4*)(p + j4) = t;
            }
        }
    }
}

// ---------------------------------------------------------------------------
extern "C" void kernel_launch(void* const* d_in, const int* in_sizes, int n_in,
                              void* d_out, int out_size, void* d_ws, size_t ws_size,
                              hipStream_t stream)
{
    const float* hidden    = (const float*)d_in[0];
    const int*   positions = (const int*)d_in[2];
    const float* in_ln_w   = (const float*)d_in[3];
    const float* post_ln_w = (const float*)d_in[4];
    const float* q_norm_w  = (const float*)d_in[5];
    const float* k_norm_w  = (const float*)d_in[6];
    const float* Wq = (const float*)d_in[7];
    const float* Wk = (const float*)d_in[8];
    const float* Wv = (const float*)d_in[9];
    const float* Wo = (const float*)d_in[10];
    const float* Wg = (const float*)d_in[11];
    const float* Wu = (const float*)d_in[12];
    const float* Wd = (const float*)d_in[13];

    float* outp   = (float*)d_out;
    float* attn   = outp + (size_t)Sn * Dm;
    float* idxout = attn + (size_t)Hn * Sn * Sn;

    // ws arena (bytes). ws >= 132 MB proven in round-1.
    char* wsb = (char*)d_ws;
    const size_t MB = 1024 * 1024;
    float* x     = (float*)(wsb + 0 * MB);    // dead after qlast_proj
    float* q     = (float*)(wsb + 16 * MB);   // dead after split
    float* kbuf  = (float*)(wsb + 32 * MB);   // dead after imp_scores
    short* x_b   = (short*)(wsb + 40 * MB);   // hi split of x
    short* WvT   = (short*)(wsb + 48 * MB);
    short* vt    = (short*)(wsb + 52 * MB);   // [kv*HD + d][token]
    short* WoT   = (short*)(wsb + 56 * MB);
    short* ctx_b = (short*)(wsb + 64 * MB);
    float* hbuf  = (float*)(wsb + 72 * MB);
    short* y_b   = (short*)(wsb + 88 * MB);
    double* qlast = (double*)(wsb + 96 * MB);
    double* qhat  = qlast + 2048;
    double* phead = qhat + 2048;
    double* ct    = phead + (size_t)Hn * Sn;
    double* st    = ct + (size_t)Sn * 64;
    // split-GEMM region (lives 99-131 MB)
    short* x_lo = (short*)(wsb + 99 * MB);    // lo split of x (8 MB)
    short* WqTh = (short*)(wsb + 107 * MB);   // 8 MB, reused as q_hi
    short* WqTl = (short*)(wsb + 115 * MB);   // 8 MB, reused as q_lo
    short* k_hi = (short*)(wsb + 123 * MB);   // 4 MB
    short* k_lo = (short*)(wsb + 127 * MB);   // 4 MB
    short* q_hi = WqTh; short* q_lo = WqTl;   // WqT dead after Q proj
    // phase-B overlays (x/q/kbuf/x_b all dead by MLP time)
    short* WgT = (short*)(wsb + 0 * MB);      // [3072][2048]
    short* WuT = (short*)(wsb + 12 * MB);
    short* hg  = (short*)(wsb + 24 * MB);     // [2048][3072]
    short* WdT = (short*)(wsb + 36 * MB);     // [2048][3072]

    const float inv_s128 = 1.0f / sqrtf(128.0f);

    // 1) input RMSNorm -> x fp32 + x_b/x_lo bf16 split
    rmsnorm_k<<<Sn, 256, 0, stream>>>(hidden, in_ln_w, x, x_b, x_lo);
    // 2) RoPE tables
    rope_table_k<<<(Sn * 64) / 256, 256, 0, stream>>>(positions, ct, st);
    // 3) weight transpose-casts: Wv (hi only), Wq (hi+lo)
    castT_k<<<dim3(1024 / 64, 2048 / 64), 256, 0, stream>>>(Wv, KVn * HD, 0, 0, WvT, nullptr, Dm);
    castT_k<<<dim3(2048 / 64, 2048 / 64), 256, 0, stream>>>(Wq, Dm, 0, 0, WqTh, WqTl, Dm);
    // 4) Q projection via split-bf16 MFMA; K projection in fp32 (importance
    //    ordering needs fp32-exact kbuf); V bf16 MFMA (transposed out)
    msplit_k<<<dim3(Dm / 128, Sn / 128, 1), 256, 0, stream>>>(
        x_b, x_lo, Dm, 0, WqTh, WqTl, Dm, 0, 0, q, Dm, 0, 1.0f, Dm, 0);
    gemm_k<float, 0><<<dim3((KVn * HD) / BN, Sn / BM, 1), 256, 0, stream>>>(
        x, Dm, 0, Wk, KVn * HD, 0, 0, kbuf, KVn * HD, 0, nullptr, Sn, KVn * HD, Dm, 1.0f, 0);
    mgemm_k<2><<<dim3((KVn * HD) / 128, Sn / 128), 256, 0, stream>>>(
        x_b, Dm, WvT, Dm, nullptr, nullptr, vt, Sn, nullptr, Dm);
    // 5) hp last-row q projection (x still live)
    qlast_proj_k<<<Dm / 64, 256, 0, stream>>>(x, Wq, qlast);
    // 6) per-head QK norm + RoPE
    qknorm_rope_k<<<Sn * Hn, 128, 0, stream>>>(q, Dm, Hn, q_norm_w, ct, st);
    qknorm_rope_k<<<Sn * KVn, 128, 0, stream>>>(kbuf, KVn * HD, KVn, k_norm_w, ct, st);
    qlast_nr_k<<<Hn, 128, 0, stream>>>(qlast, q_norm_w, ct, st, qhat);
    // 7) hi/lo split of post-rope q,k
    split_k<<<(Sn * Dm / 4) / 256, 256, 0, stream>>>(q, q_hi, q_lo, Sn * Dm / 4);
    split_k<<<(Sn * KVn * HD / 4) / 256, 256, 0, stream>>>(kbuf, k_hi, k_lo, Sn * KVn * HD / 4);
    // 8) scores via split-bf16 MFMA (causal block-skip) -> attn
    msplit_k<<<dim3(Sn / 128, Sn / 128, Hn), 256, 0, stream>>>(
        q_hi, q_lo, Dm, HD, k_hi, k_lo, KVn * HD, HD, 1,
        attn, Sn, (long long)Sn * Sn, inv_s128, HD, 1);
    // 9) causal softmax in place (wave-per-row, writes only j < E)
    softmax_k<<<(Hn * Sn) / 4, 256, 0, stream>>>(attn);
    // 10) importance (fp64) + exact sort
    imp_scores_k<<<Hn, 256, 0, stream>>>(qhat, kbuf, phead);
    imp_sort_k<<<1, 1024, 0, stream>>>(phead, idxout);
    // 11) ctx = P.V (MFMA, 64-row causal-balanced tiles) -> ctx_b bf16
    castT_k<<<dim3(2048 / 64, 2048 / 64), 256, 0, stream>>>(Wo, Dm, 0, 0, WoT, nullptr, Dm);
    ctx_k<<<dim3(1, Sn / 64, Hn), 256, 0, stream>>>(attn, vt, ctx_b);
    // 12) attn_out = ctx.Wo + hidden (MFMA)
    mgemm_k<0><<<dim3(Dm / 128, Sn / 128), 256, 0, stream>>>(
        ctx_b, Dm, WoT, Dm, nullptr, hbuf, nullptr, Dm, hidden, Dm);
    // 13) post RMSNorm -> y_b bf16
    rmsnorm_k<<<Sn, 256, 0, stream>>>(hbuf, post_ln_w, nullptr, y_b, nullptr);
    // 14) SwiGLU MLP (MFMA), 2 chunks of FF=3072
    for (int ch = 0; ch < 2; ch++) {
        castT_k<<<dim3(3072 / 64, 2048 / 64), 256, 0, stream>>>(Wg, FFn, 0, ch * 3072, WgT, nullptr, Dm);
        castT_k<<<dim3(3072 / 64, 2048 / 64), 256, 0, stream>>>(Wu, FFn, 0, ch * 3072, WuT, nullptr, Dm);
        mgemm_k<1><<<dim3(3072 / 128, Sn / 128), 256, 0, stream>>>(
            y_b, Dm, WgT, Dm, WuT, nullptr, hg, 3072, nullptr, Dm);
        castT_k<<<dim3(2048 / 64, 3072 / 64), 256, 0, stream>>>(Wd, Dm, ch * 3072, 0, WdT, nullptr, 3072);
        mgemm_k<0><<<dim3(Dm / 128, Sn / 128), 256, 0, stream>>>(
            hg, 3072, WdT, 3072, nullptr, outp, nullptr, Dm,
            (ch == 0) ? hbuf : outp, 3072);
    }
    (void)in_sizes; (void)n_in; (void)out_size; (void)ws_size;
}